// Round 1
// 7875.197 us; speedup vs baseline: 1.0559x; 1.0559x over previous
//
#include <hip/hip_runtime.h>
#include <hip/hip_bf16.h>
#include <math.h>

// Problem dims (fixed by reference)
#define I_DIM 256
#define H_DIM 512
#define B_DIM 64
#define S_DIM 512
#define SH    (S_DIM * H_DIM)        // 262144
#define S1H   ((S_DIM + 1) * H_DIM)  // 262656
#define BH    (B_DIM * H_DIM)        // 32768
#define NWG   64

typedef __bf16 bf16_t;
typedef bf16_t bf16x8 __attribute__((ext_vector_type(8)));
typedef float  f32x4  __attribute__((ext_vector_type(4)));

__device__ __forceinline__ float sigm_(float x) { return 1.0f / (1.0f + __expf(-x)); }
__device__ __forceinline__ float tanh_(float x) {
    x = fminf(fmaxf(x, -15.f), 15.f);           // avoid exp overflow -> NaN
    float e = __expf(-2.f * x);
    return (1.f - e) / (1.f + e);
}
__device__ __forceinline__ float softplus_(float x) {
    return (x > 20.0f) ? x : log1pf(__expf(x));
}
__device__ __forceinline__ unsigned short bfbits_(float f) {
    return __builtin_bit_cast(unsigned short, (bf16_t)f);
}

// Cache-bypassing (coherence-point) 16B fragment load: two relaxed agent-scope
// b64 atomic loads -> global_load_dwordx2 with sc bits, NO buffer_inv.
// NOTE: atomics are "ordered" memrefs for the scheduler -> they are never
// hoisted past other memory ops. All call sites below therefore BATCH these
// loads back-to-back in source order so they pipeline (one LLC latency per
// batch) instead of serializing one round-trip per MFMA group.
__device__ __forceinline__ bf16x8 ld_frag_agent(const bf16_t* base, int elem_idx) {
    const unsigned long long* p = (const unsigned long long*)(base) + (elem_idx >> 2);
    unsigned long long lo = __hip_atomic_load(p,     __ATOMIC_RELAXED, __HIP_MEMORY_SCOPE_AGENT);
    unsigned long long hi = __hip_atomic_load(p + 1, __ATOMIC_RELAXED, __HIP_MEMORY_SCOPE_AGENT);
    union { unsigned long long q[2]; bf16x8 v; } u;
    u.q[0] = lo; u.q[1] = hi;
    return u.v;
}

// ---------------------------------------------------------------------------
// Init (every call): zero h0 buffer + barrier state; write t=0 mu/std
// (c0 = 0 -> stats = 0 exactly -> mu0 = 1e-6, std0 = ln 2).
// ---------------------------------------------------------------------------
__global__ void k_init(bf16_t* __restrict__ hbuf0, unsigned int* __restrict__ bar,
                       float* __restrict__ out_cmu, float* __restrict__ out_cstd) {
    const int i = blockIdx.x * 256 + threadIdx.x;   // b*H + j
    hbuf0[i] = (bf16_t)0.0f;
    const int b = i >> 9, j = i & 511;
    out_cmu [b * S1H + j] = 1e-6f;
    out_cstd[b * S1H + j] = 0.69314718055994531f;
    if (i < 32) bar[i] = 0u;
}

// ---------------------------------------------------------------------------
// Persistent kernel: 64 wgs x 256 thr. wg w owns cells [8w, 8w+8) in all
// roles; wave wv owns batch rows [16wv, 16wv+16). W_hh lives in registers;
// W_ih and G fragments live in LDS (staged once) to cap register pressure.
// Per step: P (gates GEMM + cell update) -> split barrier (x/eps prefetch in
// the arrive..poll window) -> Q (stats GEMM + sampling; c_s in registers).
// ---------------------------------------------------------------------------
__global__ __launch_bounds__(256, 1) void k_persist(
    const float* __restrict__ x, const float* __restrict__ eps,
    const float* __restrict__ W_ih, const float* __restrict__ W_hh,
    const float* __restrict__ b_ih, const float* __restrict__ b_hh,
    const float* __restrict__ Gm,
    bf16_t* __restrict__ hb0, bf16_t* __restrict__ hb1,
    bf16_t* __restrict__ cn0, bf16_t* __restrict__ cn1,
    unsigned int* __restrict__ bar,
    float* __restrict__ out_hidden, float* __restrict__ out_cmu,
    float* __restrict__ out_cstd, float* __restrict__ out_hf,
    float* __restrict__ out_cf)
{
    const int w  = blockIdx.x;          // cell-slice owner (0..63)
    const int wv = threadIdx.x >> 6;    // wave -> batch quarter
    const int l  = threadIdx.x & 63;
    const int lr = l & 15;              // MFMA n (B col) / m (A row)
    const int kq = l >> 4;              // k-quad
    const int nsub   = lr & 7;          // cell within slice
    const int ghalf  = lr >> 3;         // 0: i-gate/mu lane, 1: f-gate/std lane
    const int mycell = w * 8 + nsub;
    const int col0 = ghalf * H_DIM + mycell;   // i/f col in 2048-wide gate space
    const int col1 = 1024 + col0;              // g/o col
    const int gcol = ghalf * H_DIM + mycell;   // mu/std col in 1024-wide stats
    const int row0 = wv * 16 + kq * 4;         // batch row base for C layout (+r)
    const int arow = wv * 16 + lr;             // batch row for A frags

    // LDS-resident weight fragments (identical for all 4 waves -> broadcast)
    __shared__ __align__(16) unsigned short s_wih[8][2][64][8];   // 16 KB
    __shared__ __align__(16) unsigned short s_gfr[16][64][8];     // 16 KB

    // ---- one-time: W_hh -> registers (bf16 frags) -------------------------
    bf16x8 whh0[16], whh1[16];
    #pragma unroll
    for (int kt = 0; kt < 16; ++kt) {
        const float* p0 = W_hh + (size_t)col0 * H_DIM + kt * 32 + kq * 8;
        const float* p1 = W_hh + (size_t)col1 * H_DIM + kt * 32 + kq * 8;
        bf16x8 f0, f1;
        #pragma unroll
        for (int j = 0; j < 8; ++j) { f0[j] = (bf16_t)p0[j]; f1[j] = (bf16_t)p1[j]; }
        whh0[kt] = f0; whh1[kt] = f1;
    }
    // ---- one-time: W_ih, G -> LDS (wave 0 stages; frag depends only on l) --
    if (wv == 0) {
        #pragma unroll
        for (int kt = 0; kt < 8; ++kt) {
            const float* p0 = W_ih + (size_t)col0 * I_DIM + kt * 32 + kq * 8;
            const float* p1 = W_ih + (size_t)col1 * I_DIM + kt * 32 + kq * 8;
            bf16x8 f0, f1;
            #pragma unroll
            for (int j = 0; j < 8; ++j) { f0[j] = (bf16_t)p0[j]; f1[j] = (bf16_t)p1[j]; }
            *reinterpret_cast<bf16x8*>(&s_wih[kt][0][l][0]) = f0;
            *reinterpret_cast<bf16x8*>(&s_wih[kt][1][l][0]) = f1;
        }
        #pragma unroll
        for (int kt = 0; kt < 16; ++kt) {
            bf16x8 f;
            #pragma unroll
            for (int j = 0; j < 8; ++j)
                f[j] = (bf16_t)Gm[(size_t)(kt * 32 + kq * 8 + j) * 1024 + gcol];
            *reinterpret_cast<bf16x8*>(&s_gfr[kt][l][0]) = f;
        }
    }
    const float bias0 = b_ih[col0] + b_hh[col0];
    const float bias1 = b_ih[col1] + b_hh[col1];
    __syncthreads();

    // c_s(-1) = mu0 + eps[0]*std0 (register carry; meaningful in ghalf==0 lanes)
    float csr[4];
    #pragma unroll
    for (int r = 0; r < 4; ++r)
        csr[r] = 1e-6f + eps[(size_t)(row0 + r) * H_DIM + mycell] * 0.69314718055994531f;

    // prologue: x fragments for t=0 (loads + bf16 convert)
    bf16x8 xf[8];
    #pragma unroll
    for (int kt = 0; kt < 8; ++kt) {
        const float* xp = x + (size_t)arow * (S_DIM * I_DIM) + kt * 32 + kq * 8;
        float4 u0 = reinterpret_cast<const float4*>(xp)[0];
        float4 u1 = reinterpret_cast<const float4*>(xp)[1];
        bf16x8 f;
        f[0]=(bf16_t)u0.x; f[1]=(bf16_t)u0.y; f[2]=(bf16_t)u0.z; f[3]=(bf16_t)u0.w;
        f[4]=(bf16_t)u1.x; f[5]=(bf16_t)u1.y; f[6]=(bf16_t)u1.z; f[7]=(bf16_t)u1.w;
        xf[kt] = f;
    }

    float  ev[4];       // eps(t+1) prefetch (for Q's sampling)
    float2 hv_st[4];    // deferred out_hidden payload

    #pragma unroll 1
    for (int t = 0; t < S_DIM; ++t) {
        const bf16_t* hin  = (t & 1) ? hb1 : hb0;
        bf16_t*       hout = (t & 1) ? hb0 : hb1;
        bf16_t*       cnb  = (t & 1) ? cn1 : cn0;
        unsigned int* hout_u32 = (unsigned int*)hout;
        unsigned int* cnb_u32  = (unsigned int*)cnb;

        // ============ P: gates = h @ W_hh^T + x_t @ W_ih^T =====================
        // (1) batched h loads: all 32 b64 atomics issue back-to-back -> one
        //     coherence-point latency for the whole batch.
        bf16x8 hf[16];
        #pragma unroll
        for (int kt = 0; kt < 16; ++kt)
            hf[kt] = ld_frag_agent(hin, arow * H_DIM + kt * 32 + kq * 8);

        f32x4 a0e = {0,0,0,0}, a0o = {0,0,0,0}, a1e = {0,0,0,0}, a1o = {0,0,0,0};
        #pragma unroll
        for (int kt = 0; kt < 16; kt += 2) {
            a0e = __builtin_amdgcn_mfma_f32_16x16x32_bf16(hf[kt],     whh0[kt],     a0e, 0, 0, 0);
            a1e = __builtin_amdgcn_mfma_f32_16x16x32_bf16(hf[kt],     whh1[kt],     a1e, 0, 0, 0);
            a0o = __builtin_amdgcn_mfma_f32_16x16x32_bf16(hf[kt + 1], whh0[kt + 1], a0o, 0, 0, 0);
            a1o = __builtin_amdgcn_mfma_f32_16x16x32_bf16(hf[kt + 1], whh1[kt + 1], a1o, 0, 0, 0);
        }
        // (2) x part: xf prefetched last window; W_ih streamed from LDS
        //     (ds_reads issue after the atomic batch, latency hidden by it).
        #pragma unroll
        for (int kt = 0; kt < 8; kt += 2) {
            bf16x8 w0e = *reinterpret_cast<const bf16x8*>(&s_wih[kt][0][l][0]);
            bf16x8 w1e = *reinterpret_cast<const bf16x8*>(&s_wih[kt][1][l][0]);
            bf16x8 w0o = *reinterpret_cast<const bf16x8*>(&s_wih[kt + 1][0][l][0]);
            bf16x8 w1o = *reinterpret_cast<const bf16x8*>(&s_wih[kt + 1][1][l][0]);
            a0e = __builtin_amdgcn_mfma_f32_16x16x32_bf16(xf[kt],     w0e, a0e, 0, 0, 0);
            a1e = __builtin_amdgcn_mfma_f32_16x16x32_bf16(xf[kt],     w1e, a1e, 0, 0, 0);
            a0o = __builtin_amdgcn_mfma_f32_16x16x32_bf16(xf[kt + 1], w0o, a0o, 0, 0, 0);
            a1o = __builtin_amdgcn_mfma_f32_16x16x32_bf16(xf[kt + 1], w1o, a1o, 0, 0, 0);
        }
        f32x4 a0 = a0e + a0o, a1 = a1e + a1o;

        // ---- pointwise cell update; ONLY h/c (cross-wg) stores issue now; ----
        // ---- out_hidden payload kept in regs and stored after the arrive. ----
        #pragma unroll
        for (int r = 0; r < 4; ++r) {
            float sif = sigm_(a0[r] + bias0);                       // i or f
            float v1  = a1[r] + bias1;
            float go  = (ghalf == 0) ? tanh_(v1) : sigm_(v1);       // g or o
            float fv  = __shfl_xor(sif, 8);
            float ov  = __shfl_xor(go, 8);
            float cn  = fv * csr[r] + sif * go;
            float hn  = ov * tanh_(cn);
            unsigned hcw = ((unsigned)bfbits_(cn) << 16) | (unsigned)bfbits_(hn);
            unsigned pp  = __shfl_xor(hcw, 1);                      // partner cell
            float    hp  = __shfl_xor(hn, 1);
            hv_st[r].x = hn; hv_st[r].y = hp;
            if (ghalf == 0 && !(lr & 1)) {
                const int row  = row0 + r;
                const int cidx = (row * H_DIM + mycell) >> 1;       // u32 index
                unsigned hw = ((pp & 0xFFFFu) << 16) | (hcw & 0xFFFFu);
                unsigned cw = (pp & 0xFFFF0000u)     | (hcw >> 16);
                __hip_atomic_store(hout_u32 + cidx, hw, __ATOMIC_RELAXED, __HIP_MEMORY_SCOPE_AGENT);
                __hip_atomic_store(cnb_u32  + cidx, cw, __ATOMIC_RELAXED, __HIP_MEMORY_SCOPE_AGENT);
            }
        }

        // ============ split barrier: arrive -> prefetch window -> poll =========
        __threadfence_block();            // drain h/c stores to coherence point
        __syncthreads();
        if (threadIdx.x == 0)
            __hip_atomic_fetch_add(&bar[0], 1u, __ATOMIC_RELAXED, __HIP_MEMORY_SCOPE_AGENT);

        // hidden under barrier wait: x(t+1) load+convert, eps(t+1) loads
        if (t + 1 < S_DIM) {
            #pragma unroll
            for (int kt = 0; kt < 8; ++kt) {
                const float* xp = x + (size_t)arow * (S_DIM * I_DIM)
                                    + (size_t)(t + 1) * I_DIM + kt * 32 + kq * 8;
                float4 u0 = reinterpret_cast<const float4*>(xp)[0];
                float4 u1 = reinterpret_cast<const float4*>(xp)[1];
                bf16x8 f;
                f[0]=(bf16_t)u0.x; f[1]=(bf16_t)u0.y; f[2]=(bf16_t)u0.z; f[3]=(bf16_t)u0.w;
                f[4]=(bf16_t)u1.x; f[5]=(bf16_t)u1.y; f[6]=(bf16_t)u1.z; f[7]=(bf16_t)u1.w;
                xf[kt] = f;
            }
        }
        #pragma unroll
        for (int r = 0; r < 4; ++r)
            ev[r] = eps[(size_t)(t + 1) * BH + (size_t)(row0 + r) * H_DIM + mycell];

        if (threadIdx.x == 0) {
            const unsigned target = (unsigned)(t + 1) * NWG;
            while (__hip_atomic_load(&bar[0], __ATOMIC_RELAXED, __HIP_MEMORY_SCOPE_AGENT) < target)
                __builtin_amdgcn_s_sleep(1);
        }
        __syncthreads();
        __atomic_signal_fence(__ATOMIC_ACQUIRE);   // compiler-only ordering

        // ============ Q: stats = c_new @ G; sample =============================
        // batched c loads first (one LLC latency for the batch) ...
        bf16x8 cf[16];
        #pragma unroll
        for (int kt = 0; kt < 16; ++kt)
            cf[kt] = ld_frag_agent(cnb, arow * H_DIM + kt * 32 + kq * 8);

        // ... then deferred output stores issue while cf is in flight (they sit
        // AFTER the loads in vmcnt order, so MFMA waits don't drain them).
        if (ghalf == 0 && !(lr & 1)) {
            #pragma unroll
            for (int r = 0; r < 4; ++r)
                *(float2*)(out_hidden + (size_t)(row0 + r) * SH + (size_t)t * H_DIM + mycell) = hv_st[r];
            if (t == S_DIM - 1) {
                #pragma unroll
                for (int r = 0; r < 4; ++r)
                    *(float2*)(out_hf + (row0 + r) * H_DIM + mycell) = hv_st[r];
            }
        }

        f32x4 se = {0,0,0,0}, so = {0,0,0,0};
        #pragma unroll
        for (int kt = 0; kt < 16; kt += 2) {
            bf16x8 g0 = *reinterpret_cast<const bf16x8*>(&s_gfr[kt][l][0]);
            bf16x8 g1 = *reinterpret_cast<const bf16x8*>(&s_gfr[kt + 1][l][0]);
            se = __builtin_amdgcn_mfma_f32_16x16x32_bf16(cf[kt],     g0, se, 0, 0, 0);
            so = __builtin_amdgcn_mfma_f32_16x16x32_bf16(cf[kt + 1], g1, so, 0, 0, 0);
        }
        f32x4 st = se + so;
        #pragma unroll
        for (int r = 0; r < 4; ++r) {
            const int row = row0 + r;
            float sv  = st[r];
            float muv = fminf(fmaxf(sv, 1e-6f), 1e6f);
            float sdv = fmaxf(softplus_(sv), 1e-6f);
            float outv = (ghalf == 0) ? muv : sdv;
            float op   = __shfl_xor(outv, 1);       // partner cell's value
            if (!(lr & 1)) {
                float* outp = ((ghalf == 0) ? out_cmu : out_cstd)
                              + (size_t)row * S1H + (size_t)(t + 1) * H_DIM + mycell;
                float2 v2; v2.x = outv; v2.y = op;
                *(float2*)outp = v2;
            }
            float sd_p = __shfl_xor(outv, 8);       // ghalf==0 gets partner's std
            csr[r] = muv + ev[r] * sd_p;            // register carry of c_s
            if (t == S_DIM - 1 && ghalf == 0) out_cf[row * H_DIM + mycell] = csr[r];
        }
        // no second barrier: P(t+1) reads only h(t+1) (visible) and local csr
    }
}

// ---------------------------------------------------------------------------
extern "C" void kernel_launch(void* const* d_in, const int* in_sizes, int n_in,
                              void* d_out, int out_size, void* d_ws, size_t ws_size,
                              hipStream_t stream) {
    (void)in_sizes; (void)n_in; (void)out_size; (void)ws_size;

    const float* x    = (const float*)d_in[0];  // (B,S,I)
    const float* eps  = (const float*)d_in[1];  // (S+1,B,H)
    const float* W_ih = (const float*)d_in[2];  // (4H,I)
    const float* W_hh = (const float*)d_in[3];  // (4H,H)
    const float* b_ih = (const float*)d_in[4];  // (4H,)
    const float* b_hh = (const float*)d_in[5];  // (4H,)
    const float* Gm   = (const float*)d_in[6];  // (H,2H)

    float* out        = (float*)d_out;
    float* out_hidden = out;                                   // (B,S,H)
    float* out_cmu    = out_hidden + (size_t)B_DIM * SH;       // (B,S+1,H)
    float* out_cstd   = out_cmu + (size_t)B_DIM * S1H;         // (B,S+1,H)
    float* out_hf     = out_cstd + (size_t)B_DIM * S1H;        // (B,H)
    float* out_cf     = out_hf + (size_t)B_DIM * H_DIM;        // (B,H)

    // workspace carve (~260 KB)
    char* wsb = (char*)d_ws;
    bf16_t* hb0 = (bf16_t*)(wsb);                     // 64 KB  h double-buffer
    bf16_t* hb1 = (bf16_t*)(wsb + (1u << 16));        // 64 KB
    bf16_t* cn0 = (bf16_t*)(wsb + 2u * (1u << 16));   // 64 KB  c_new double-buffer
    bf16_t* cn1 = (bf16_t*)(wsb + 3u * (1u << 16));   // 64 KB
    unsigned int* bar = (unsigned int*)(wsb + 4u * (1u << 16)); // barrier state

    k_init<<<dim3(128), dim3(256), 0, stream>>>(hb0, bar, out_cmu, out_cstd);
    k_persist<<<dim3(NWG), dim3(256), 0, stream>>>(
        x, eps, W_ih, W_hh, b_ih, b_hh, Gm,
        hb0, hb1, cn0, cn1, bar,
        out_hidden, out_cmu, out_cstd, out_hf, out_cf);
}

// Round 2
// 7770.361 us; speedup vs baseline: 1.0701x; 1.0135x over previous
//
#include <hip/hip_runtime.h>
#include <hip/hip_bf16.h>
#include <math.h>

// Problem dims (fixed by reference)
#define I_DIM 256
#define H_DIM 512
#define B_DIM 64
#define S_DIM 512
#define SH    (S_DIM * H_DIM)        // 262144
#define S1H   ((S_DIM + 1) * H_DIM)  // 262656
#define BH    (B_DIM * H_DIM)        // 32768
#define NWG   64

typedef __bf16 bf16_t;
typedef bf16_t bf16x8 __attribute__((ext_vector_type(8)));
typedef float  f32x4  __attribute__((ext_vector_type(4)));

__device__ __forceinline__ float sigm_(float x) { return 1.0f / (1.0f + __expf(-x)); }
__device__ __forceinline__ float tanh_(float x) {
    x = fminf(fmaxf(x, -15.f), 15.f);           // avoid exp overflow -> NaN
    float e = __expf(-2.f * x);
    return (1.f - e) / (1.f + e);
}
__device__ __forceinline__ float softplus_(float x) {
    return (x > 20.0f) ? x : log1pf(__expf(x));
}
__device__ __forceinline__ unsigned short bfbits_(float f) {
    return __builtin_bit_cast(unsigned short, (bf16_t)f);
}

// Cache-bypassing (coherence-point) 16B fragment load: two relaxed agent-scope
// b64 atomic loads -> global_load_dwordx2 with sc bits, NO buffer_inv.
// Atomics are "ordered" memrefs for the scheduler, so call sites BATCH these
// back-to-back (one LLC latency per batch, pipelined via vmcnt).
__device__ __forceinline__ bf16x8 ld_frag_agent(const bf16_t* base, int elem_idx) {
    const unsigned long long* p = (const unsigned long long*)(base) + (elem_idx >> 2);
    unsigned long long lo = __hip_atomic_load(p,     __ATOMIC_RELAXED, __HIP_MEMORY_SCOPE_AGENT);
    unsigned long long hi = __hip_atomic_load(p + 1, __ATOMIC_RELAXED, __HIP_MEMORY_SCOPE_AGENT);
    union { unsigned long long q[2]; bf16x8 v; } u;
    u.q[0] = lo; u.q[1] = hi;
    return u.v;
}

// ---------------------------------------------------------------------------
// Init (every call): zero h0 buffer + ALL 64 barrier slots; write t=0 mu/std
// (c0 = 0 -> stats = 0 exactly -> mu0 = 1e-6, std0 = ln 2).
// ---------------------------------------------------------------------------
__global__ void k_init(bf16_t* __restrict__ hbuf0, unsigned int* __restrict__ bar,
                       float* __restrict__ out_cmu, float* __restrict__ out_cstd) {
    const int i = blockIdx.x * 256 + threadIdx.x;   // b*H + j
    hbuf0[i] = (bf16_t)0.0f;
    const int b = i >> 9, j = i & 511;
    out_cmu [b * S1H + j] = 1e-6f;
    out_cstd[b * S1H + j] = 0.69314718055994531f;
    if (i < 64) bar[i] = 0u;
}

// ---------------------------------------------------------------------------
// Persistent kernel: 64 wgs x 256 thr. wg w owns cells [8w, 8w+8) in all
// roles; wave wv owns batch rows [16wv, 16wv+16). W_hh in registers; W_ih/G
// fragments in LDS. Per step:
//   P  (gates GEMM from REGISTER h-fragments + x; pointwise; h/c stores)
//   arrive: per-WG flag STORE bar[w]=t+1 (no RMW)  -> x/eps prefetch window
//   poll:   wave 0, lane l loads bar[l]; __all(>=t+1) = one round-trip check
//   Q  (batched c loads + NEXT-STEP h loads co-issued; stats GEMM; sampling)
// ---------------------------------------------------------------------------
__global__ __launch_bounds__(256, 1) void k_persist(
    const float* __restrict__ x, const float* __restrict__ eps,
    const float* __restrict__ W_ih, const float* __restrict__ W_hh,
    const float* __restrict__ b_ih, const float* __restrict__ b_hh,
    const float* __restrict__ Gm,
    bf16_t* __restrict__ hb0, bf16_t* __restrict__ hb1,
    bf16_t* __restrict__ cn0, bf16_t* __restrict__ cn1,
    unsigned int* __restrict__ bar,
    float* __restrict__ out_hidden, float* __restrict__ out_cmu,
    float* __restrict__ out_cstd, float* __restrict__ out_hf,
    float* __restrict__ out_cf)
{
    const int w  = blockIdx.x;          // cell-slice owner (0..63)
    const int wv = threadIdx.x >> 6;    // wave -> batch quarter
    const int l  = threadIdx.x & 63;
    const int lr = l & 15;              // MFMA n (B col) / m (A row)
    const int kq = l >> 4;              // k-quad
    const int nsub   = lr & 7;          // cell within slice
    const int ghalf  = lr >> 3;         // 0: i-gate/mu lane, 1: f-gate/std lane
    const int mycell = w * 8 + nsub;
    const int col0 = ghalf * H_DIM + mycell;   // i/f col in 2048-wide gate space
    const int col1 = 1024 + col0;              // g/o col
    const int gcol = ghalf * H_DIM + mycell;   // mu/std col in 1024-wide stats
    const int row0 = wv * 16 + kq * 4;         // batch row base for C layout (+r)
    const int arow = wv * 16 + lr;             // batch row for A frags

    // LDS-resident weight fragments (identical for all 4 waves -> broadcast)
    __shared__ __align__(16) unsigned short s_wih[8][2][64][8];   // 16 KB
    __shared__ __align__(16) unsigned short s_gfr[16][64][8];     // 16 KB

    // ---- one-time: W_hh -> registers (bf16 frags) -------------------------
    bf16x8 whh0[16], whh1[16];
    #pragma unroll
    for (int kt = 0; kt < 16; ++kt) {
        const float* p0 = W_hh + (size_t)col0 * H_DIM + kt * 32 + kq * 8;
        const float* p1 = W_hh + (size_t)col1 * H_DIM + kt * 32 + kq * 8;
        bf16x8 f0, f1;
        #pragma unroll
        for (int j = 0; j < 8; ++j) { f0[j] = (bf16_t)p0[j]; f1[j] = (bf16_t)p1[j]; }
        whh0[kt] = f0; whh1[kt] = f1;
    }
    // ---- one-time: W_ih, G -> LDS (wave 0 stages; frag depends only on l) --
    if (wv == 0) {
        #pragma unroll
        for (int kt = 0; kt < 8; ++kt) {
            const float* p0 = W_ih + (size_t)col0 * I_DIM + kt * 32 + kq * 8;
            const float* p1 = W_ih + (size_t)col1 * I_DIM + kt * 32 + kq * 8;
            bf16x8 f0, f1;
            #pragma unroll
            for (int j = 0; j < 8; ++j) { f0[j] = (bf16_t)p0[j]; f1[j] = (bf16_t)p1[j]; }
            *reinterpret_cast<bf16x8*>(&s_wih[kt][0][l][0]) = f0;
            *reinterpret_cast<bf16x8*>(&s_wih[kt][1][l][0]) = f1;
        }
        #pragma unroll
        for (int kt = 0; kt < 16; ++kt) {
            bf16x8 f;
            #pragma unroll
            for (int j = 0; j < 8; ++j)
                f[j] = (bf16_t)Gm[(size_t)(kt * 32 + kq * 8 + j) * 1024 + gcol];
            *reinterpret_cast<bf16x8*>(&s_gfr[kt][l][0]) = f;
        }
    }
    const float bias0 = b_ih[col0] + b_hh[col0];
    const float bias1 = b_ih[col1] + b_hh[col1];
    __syncthreads();

    // c_s(-1) = mu0 + eps[0]*std0 (register carry; meaningful in ghalf==0 lanes)
    float csr[4];
    #pragma unroll
    for (int r = 0; r < 4; ++r)
        csr[r] = 1e-6f + eps[(size_t)(row0 + r) * H_DIM + mycell] * 0.69314718055994531f;

    // prologue: x fragments for t=0 (loads + bf16 convert)
    bf16x8 xf[8];
    #pragma unroll
    for (int kt = 0; kt < 8; ++kt) {
        const float* xp = x + (size_t)arow * (S_DIM * I_DIM) + kt * 32 + kq * 8;
        float4 u0 = reinterpret_cast<const float4*>(xp)[0];
        float4 u1 = reinterpret_cast<const float4*>(xp)[1];
        bf16x8 f;
        f[0]=(bf16_t)u0.x; f[1]=(bf16_t)u0.y; f[2]=(bf16_t)u0.z; f[3]=(bf16_t)u0.w;
        f[4]=(bf16_t)u1.x; f[5]=(bf16_t)u1.y; f[6]=(bf16_t)u1.z; f[7]=(bf16_t)u1.w;
        xf[kt] = f;
    }

    // h(0) = 0 -> first-step h fragments are register zeros (no load needed)
    bf16x8 hf[16];
    #pragma unroll
    for (int kt = 0; kt < 16; ++kt) {
        bf16x8 z;
        #pragma unroll
        for (int j = 0; j < 8; ++j) z[j] = (bf16_t)0.0f;
        hf[kt] = z;
    }

    float  ev[4];       // eps(t+1) prefetch (for Q's sampling)
    float2 hv_st[4];    // deferred out_hidden payload

    #pragma unroll 1
    for (int t = 0; t < S_DIM; ++t) {
        bf16_t*       hout = (t & 1) ? hb0 : hb1;
        bf16_t*       cnb  = (t & 1) ? cn1 : cn0;
        unsigned int* hout_u32 = (unsigned int*)hout;
        unsigned int* cnb_u32  = (unsigned int*)cnb;

        // ============ P: gates = h @ W_hh^T + x_t @ W_ih^T =====================
        // h fragments already in registers (loaded during previous Q / zeros).
        f32x4 a0e = {0,0,0,0}, a0o = {0,0,0,0}, a1e = {0,0,0,0}, a1o = {0,0,0,0};
        #pragma unroll
        for (int kt = 0; kt < 16; kt += 2) {
            a0e = __builtin_amdgcn_mfma_f32_16x16x32_bf16(hf[kt],     whh0[kt],     a0e, 0, 0, 0);
            a1e = __builtin_amdgcn_mfma_f32_16x16x32_bf16(hf[kt],     whh1[kt],     a1e, 0, 0, 0);
            a0o = __builtin_amdgcn_mfma_f32_16x16x32_bf16(hf[kt + 1], whh0[kt + 1], a0o, 0, 0, 0);
            a1o = __builtin_amdgcn_mfma_f32_16x16x32_bf16(hf[kt + 1], whh1[kt + 1], a1o, 0, 0, 0);
        }
        // x part: xf prefetched in last barrier window; W_ih streamed from LDS
        #pragma unroll
        for (int kt = 0; kt < 8; kt += 2) {
            bf16x8 w0e = *reinterpret_cast<const bf16x8*>(&s_wih[kt][0][l][0]);
            bf16x8 w1e = *reinterpret_cast<const bf16x8*>(&s_wih[kt][1][l][0]);
            bf16x8 w0o = *reinterpret_cast<const bf16x8*>(&s_wih[kt + 1][0][l][0]);
            bf16x8 w1o = *reinterpret_cast<const bf16x8*>(&s_wih[kt + 1][1][l][0]);
            a0e = __builtin_amdgcn_mfma_f32_16x16x32_bf16(xf[kt],     w0e, a0e, 0, 0, 0);
            a1e = __builtin_amdgcn_mfma_f32_16x16x32_bf16(xf[kt],     w1e, a1e, 0, 0, 0);
            a0o = __builtin_amdgcn_mfma_f32_16x16x32_bf16(xf[kt + 1], w0o, a0o, 0, 0, 0);
            a1o = __builtin_amdgcn_mfma_f32_16x16x32_bf16(xf[kt + 1], w1o, a1o, 0, 0, 0);
        }
        f32x4 a0 = a0e + a0o, a1 = a1e + a1o;

        // ---- pointwise cell update; ONLY h/c (cross-wg) stores issue now ------
        #pragma unroll
        for (int r = 0; r < 4; ++r) {
            float sif = sigm_(a0[r] + bias0);                       // i or f
            float v1  = a1[r] + bias1;
            float go  = (ghalf == 0) ? tanh_(v1) : sigm_(v1);       // g or o
            float fv  = __shfl_xor(sif, 8);
            float ov  = __shfl_xor(go, 8);
            float cn  = fv * csr[r] + sif * go;
            float hn  = ov * tanh_(cn);
            unsigned hcw = ((unsigned)bfbits_(cn) << 16) | (unsigned)bfbits_(hn);
            unsigned pp  = __shfl_xor(hcw, 1);                      // partner cell
            float    hp  = __shfl_xor(hn, 1);
            hv_st[r].x = hn; hv_st[r].y = hp;
            if (ghalf == 0 && !(lr & 1)) {
                const int row  = row0 + r;
                const int cidx = (row * H_DIM + mycell) >> 1;       // u32 index
                unsigned hw = ((pp & 0xFFFFu) << 16) | (hcw & 0xFFFFu);
                unsigned cw = (pp & 0xFFFF0000u)     | (hcw >> 16);
                __hip_atomic_store(hout_u32 + cidx, hw, __ATOMIC_RELAXED, __HIP_MEMORY_SCOPE_AGENT);
                __hip_atomic_store(cnb_u32  + cidx, cw, __ATOMIC_RELAXED, __HIP_MEMORY_SCOPE_AGENT);
            }
        }

        // ============ distributed barrier: arrive(store) -> prefetch -> poll ===
        __threadfence_block();            // drain h/c stores to coherence point
        __syncthreads();
        if (threadIdx.x == 0)             // per-WG flag store, NO RMW
            __hip_atomic_store(&bar[w], (unsigned)(t + 1),
                               __ATOMIC_RELAXED, __HIP_MEMORY_SCOPE_AGENT);

        // hidden under barrier wait: x(t+1) load+convert, eps(t+1) loads
        if (t + 1 < S_DIM) {
            #pragma unroll
            for (int kt = 0; kt < 8; ++kt) {
                const float* xp = x + (size_t)arow * (S_DIM * I_DIM)
                                    + (size_t)(t + 1) * I_DIM + kt * 32 + kq * 8;
                float4 u0 = reinterpret_cast<const float4*>(xp)[0];
                float4 u1 = reinterpret_cast<const float4*>(xp)[1];
                bf16x8 f;
                f[0]=(bf16_t)u0.x; f[1]=(bf16_t)u0.y; f[2]=(bf16_t)u0.z; f[3]=(bf16_t)u0.w;
                f[4]=(bf16_t)u1.x; f[5]=(bf16_t)u1.y; f[6]=(bf16_t)u1.z; f[7]=(bf16_t)u1.w;
                xf[kt] = f;
            }
        }
        #pragma unroll
        for (int r = 0; r < 4; ++r)
            ev[r] = eps[(size_t)(t + 1) * BH + (size_t)(row0 + r) * H_DIM + mycell];

        // lane-parallel poll: lane l watches wg l's flag; one load = all 64
        if (wv == 0) {
            const unsigned target = (unsigned)(t + 1);
            while (true) {
                unsigned v = __hip_atomic_load(&bar[l], __ATOMIC_RELAXED,
                                               __HIP_MEMORY_SCOPE_AGENT);
                if (__all((int)(v >= target))) break;
                __builtin_amdgcn_s_sleep(1);
            }
        }
        __syncthreads();
        __atomic_signal_fence(__ATOMIC_ACQUIRE);   // compiler-only ordering

        // ============ Q: stats = c_new @ G; sample =============================
        // batched c loads, then NEXT-STEP h loads co-issued (hout(t) is visible
        // after the barrier; latency hides under Q's MFMAs + sampling).
        bf16x8 cf[16];
        #pragma unroll
        for (int kt = 0; kt < 16; ++kt)
            cf[kt] = ld_frag_agent(cnb, arow * H_DIM + kt * 32 + kq * 8);
        #pragma unroll
        for (int kt = 0; kt < 16; ++kt)
            hf[kt] = ld_frag_agent(hout, arow * H_DIM + kt * 32 + kq * 8);

        // deferred output stores issue while cf/hf are in flight
        if (ghalf == 0 && !(lr & 1)) {
            #pragma unroll
            for (int r = 0; r < 4; ++r)
                *(float2*)(out_hidden + (size_t)(row0 + r) * SH + (size_t)t * H_DIM + mycell) = hv_st[r];
            if (t == S_DIM - 1) {
                #pragma unroll
                for (int r = 0; r < 4; ++r)
                    *(float2*)(out_hf + (row0 + r) * H_DIM + mycell) = hv_st[r];
            }
        }

        f32x4 se = {0,0,0,0}, so = {0,0,0,0};
        #pragma unroll
        for (int kt = 0; kt < 16; kt += 2) {
            bf16x8 g0 = *reinterpret_cast<const bf16x8*>(&s_gfr[kt][l][0]);
            bf16x8 g1 = *reinterpret_cast<const bf16x8*>(&s_gfr[kt + 1][l][0]);
            se = __builtin_amdgcn_mfma_f32_16x16x32_bf16(cf[kt],     g0, se, 0, 0, 0);
            so = __builtin_amdgcn_mfma_f32_16x16x32_bf16(cf[kt + 1], g1, so, 0, 0, 0);
        }
        f32x4 st = se + so;
        #pragma unroll
        for (int r = 0; r < 4; ++r) {
            const int row = row0 + r;
            float sv  = st[r];
            float muv = fminf(fmaxf(sv, 1e-6f), 1e6f);
            float sdv = fmaxf(softplus_(sv), 1e-6f);
            float outv = (ghalf == 0) ? muv : sdv;
            float op   = __shfl_xor(outv, 1);       // partner cell's value
            if (!(lr & 1)) {
                float* outp = ((ghalf == 0) ? out_cmu : out_cstd)
                              + (size_t)row * S1H + (size_t)(t + 1) * H_DIM + mycell;
                float2 v2; v2.x = outv; v2.y = op;
                *(float2*)outp = v2;
            }
            float sd_p = __shfl_xor(outv, 8);       // ghalf==0 gets partner's std
            csr[r] = muv + ev[r] * sd_p;            // register carry of c_s
            if (t == S_DIM - 1 && ghalf == 0) out_cf[row * H_DIM + mycell] = csr[r];
        }
        // no second barrier: P(t+1) reads only register hf (loaded above) + csr
    }
}

// ---------------------------------------------------------------------------
extern "C" void kernel_launch(void* const* d_in, const int* in_sizes, int n_in,
                              void* d_out, int out_size, void* d_ws, size_t ws_size,
                              hipStream_t stream) {
    (void)in_sizes; (void)n_in; (void)out_size; (void)ws_size;

    const float* x    = (const float*)d_in[0];  // (B,S,I)
    const float* eps  = (const float*)d_in[1];  // (S+1,B,H)
    const float* W_ih = (const float*)d_in[2];  // (4H,I)
    const float* W_hh = (const float*)d_in[3];  // (4H,H)
    const float* b_ih = (const float*)d_in[4];  // (4H,)
    const float* b_hh = (const float*)d_in[5];  // (4H,)
    const float* Gm   = (const float*)d_in[6];  // (H,2H)

    float* out        = (float*)d_out;
    float* out_hidden = out;                                   // (B,S,H)
    float* out_cmu    = out_hidden + (size_t)B_DIM * SH;       // (B,S+1,H)
    float* out_cstd   = out_cmu + (size_t)B_DIM * S1H;         // (B,S+1,H)
    float* out_hf     = out_cstd + (size_t)B_DIM * S1H;        // (B,H)
    float* out_cf     = out_hf + (size_t)B_DIM * H_DIM;        // (B,H)

    // workspace carve (~260 KB)
    char* wsb = (char*)d_ws;
    bf16_t* hb0 = (bf16_t*)(wsb);                     // 64 KB  h double-buffer
    bf16_t* hb1 = (bf16_t*)(wsb + (1u << 16));        // 64 KB
    bf16_t* cn0 = (bf16_t*)(wsb + 2u * (1u << 16));   // 64 KB  c_new double-buffer
    bf16_t* cn1 = (bf16_t*)(wsb + 3u * (1u << 16));   // 64 KB
    unsigned int* bar = (unsigned int*)(wsb + 4u * (1u << 16)); // barrier (64 slots)

    k_init<<<dim3(128), dim3(256), 0, stream>>>(hb0, bar, out_cmu, out_cstd);
    k_persist<<<dim3(NWG), dim3(256), 0, stream>>>(
        x, eps, W_ih, W_hh, b_ih, b_hh, Gm,
        hb0, hb1, cn0, cn1, bar,
        out_hidden, out_cmu, out_cstd, out_hf, out_cf);
}

// Round 4
// 5850.801 us; speedup vs baseline: 1.4212x; 1.3281x over previous
//
#include <hip/hip_runtime.h>
#include <hip/hip_bf16.h>
#include <math.h>

// Problem dims (fixed by reference)
#define I_DIM 256
#define H_DIM 512
#define B_DIM 64
#define S_DIM 512
#define SH    (S_DIM * H_DIM)        // 262144
#define S1H   ((S_DIM + 1) * H_DIM)  // 262656
#define BH    (B_DIM * H_DIM)        // 32768
#define NWG   64

typedef __bf16 bf16_t;
typedef bf16_t bf16x8 __attribute__((ext_vector_type(8)));
typedef float  f32x4  __attribute__((ext_vector_type(4)));
typedef float  f32x2  __attribute__((ext_vector_type(2)));   // clang vector: OK for nontemporal builtins

__device__ __forceinline__ float sigm_(float x) { return 1.0f / (1.0f + __expf(-x)); }
__device__ __forceinline__ float tanh_(float x) {
    x = fminf(fmaxf(x, -15.f), 15.f);           // avoid exp overflow -> NaN
    float e = __expf(-2.f * x);
    return (1.f - e) / (1.f + e);
}
__device__ __forceinline__ float softplus_(float x) {
    return (x > 20.0f) ? x : log1pf(__expf(x));
}
__device__ __forceinline__ unsigned short bfbits_(float f) {
    return __builtin_bit_cast(unsigned short, (bf16_t)f);
}

// Plain cached 16B fragment load. Coherence is provided by the per-step
// agent-scope ACQUIRE fence (L1+L2 invalidate) executed after barrier detect:
// producer's agent-scope write-through stores are at the LLC before its flag,
// consumer's post-fence loads miss L2 and fetch fresh lines. 8 WGs per XCD
// share one L2 fill of the exchanged state (vs agent loads: 0 reuse).
__device__ __forceinline__ bf16x8 ld_frag(const bf16_t* base, int elem_idx) {
    return *reinterpret_cast<const bf16x8*>(base + elem_idx);
}

// ---------------------------------------------------------------------------
// Init (every call): zero h0 buffer + ALL 64 barrier slots; write t=0 mu/std
// (c0 = 0 -> stats = 0 exactly -> mu0 = 1e-6, std0 = ln 2).
// ---------------------------------------------------------------------------
__global__ void k_init(bf16_t* __restrict__ hbuf0, unsigned int* __restrict__ bar,
                       float* __restrict__ out_cmu, float* __restrict__ out_cstd) {
    const int i = blockIdx.x * 256 + threadIdx.x;   // b*H + j
    hbuf0[i] = (bf16_t)0.0f;
    const int b = i >> 9, j = i & 511;
    out_cmu [b * S1H + j] = 1e-6f;
    out_cstd[b * S1H + j] = 0.69314718055994531f;
    if (i < 64) bar[i] = 0u;
}

// ---------------------------------------------------------------------------
// Persistent kernel: 64 wgs x 256 thr. wg w owns cells [8w, 8w+8) in all
// roles; wave wv owns batch rows [16wv, 16wv+16). W_hh in registers; W_ih/G
// fragments in LDS. Per step:
//   P  (gates GEMM from REGISTER h-fragments + x; pointwise; h/c agent stores)
//   arrive: per-WG flag STORE bar[w]=t+1 (no RMW)  -> x/eps prefetch window
//   poll:   wave 0, lane l loads bar[l]; __all(>=t+1) = one round-trip check
//   acquire fence (agent): invalidate L1/L2 so cached loads see fresh state
//   Q  (cached c loads + NEXT-STEP h loads co-issued; stats GEMM; sampling)
// All out_* stores are NON-TEMPORAL: scattered 8B float2 stores at 2KB stride
// otherwise trigger write-allocate RFO (HBM line read per store) which both
// inflates FETCH_SIZE (~200MB) and puts HBM latency into the pre-flag
// vmcnt-drain on the barrier critical path.
// ---------------------------------------------------------------------------
__global__ __launch_bounds__(256, 1) void k_persist(
    const float* __restrict__ x, const float* __restrict__ eps,
    const float* __restrict__ W_ih, const float* __restrict__ W_hh,
    const float* __restrict__ b_ih, const float* __restrict__ b_hh,
    const float* __restrict__ Gm,
    bf16_t* __restrict__ hb0, bf16_t* __restrict__ hb1,
    bf16_t* __restrict__ cn0, bf16_t* __restrict__ cn1,
    unsigned int* __restrict__ bar,
    float* __restrict__ out_hidden, float* __restrict__ out_cmu,
    float* __restrict__ out_cstd, float* __restrict__ out_hf,
    float* __restrict__ out_cf)
{
    const int w  = blockIdx.x;          // cell-slice owner (0..63)
    const int wv = threadIdx.x >> 6;    // wave -> batch quarter
    const int l  = threadIdx.x & 63;
    const int lr = l & 15;              // MFMA n (B col) / m (A row)
    const int kq = l >> 4;              // k-quad
    const int nsub   = lr & 7;          // cell within slice
    const int ghalf  = lr >> 3;         // 0: i-gate/mu lane, 1: f-gate/std lane
    const int mycell = w * 8 + nsub;
    const int col0 = ghalf * H_DIM + mycell;   // i/f col in 2048-wide gate space
    const int col1 = 1024 + col0;              // g/o col
    const int gcol = ghalf * H_DIM + mycell;   // mu/std col in 1024-wide stats
    const int row0 = wv * 16 + kq * 4;         // batch row base for C layout (+r)
    const int arow = wv * 16 + lr;             // batch row for A frags

    // LDS-resident weight fragments (identical for all 4 waves -> broadcast)
    __shared__ __align__(16) unsigned short s_wih[8][2][64][8];   // 16 KB
    __shared__ __align__(16) unsigned short s_gfr[16][64][8];     // 16 KB

    // ---- one-time: W_hh -> registers (bf16 frags) -------------------------
    bf16x8 whh0[16], whh1[16];
    #pragma unroll
    for (int kt = 0; kt < 16; ++kt) {
        const float* p0 = W_hh + (size_t)col0 * H_DIM + kt * 32 + kq * 8;
        const float* p1 = W_hh + (size_t)col1 * H_DIM + kt * 32 + kq * 8;
        bf16x8 f0, f1;
        #pragma unroll
        for (int j = 0; j < 8; ++j) { f0[j] = (bf16_t)p0[j]; f1[j] = (bf16_t)p1[j]; }
        whh0[kt] = f0; whh1[kt] = f1;
    }
    // ---- one-time: W_ih, G -> LDS (wave 0 stages; frag depends only on l) --
    if (wv == 0) {
        #pragma unroll
        for (int kt = 0; kt < 8; ++kt) {
            const float* p0 = W_ih + (size_t)col0 * I_DIM + kt * 32 + kq * 8;
            const float* p1 = W_ih + (size_t)col1 * I_DIM + kt * 32 + kq * 8;
            bf16x8 f0, f1;
            #pragma unroll
            for (int j = 0; j < 8; ++j) { f0[j] = (bf16_t)p0[j]; f1[j] = (bf16_t)p1[j]; }
            *reinterpret_cast<bf16x8*>(&s_wih[kt][0][l][0]) = f0;
            *reinterpret_cast<bf16x8*>(&s_wih[kt][1][l][0]) = f1;
        }
        #pragma unroll
        for (int kt = 0; kt < 16; ++kt) {
            bf16x8 f;
            #pragma unroll
            for (int j = 0; j < 8; ++j)
                f[j] = (bf16_t)Gm[(size_t)(kt * 32 + kq * 8 + j) * 1024 + gcol];
            *reinterpret_cast<bf16x8*>(&s_gfr[kt][l][0]) = f;
        }
    }
    const float bias0 = b_ih[col0] + b_hh[col0];
    const float bias1 = b_ih[col1] + b_hh[col1];
    __syncthreads();

    // c_s(-1) = mu0 + eps[0]*std0 (register carry; meaningful in ghalf==0 lanes)
    float csr[4];
    #pragma unroll
    for (int r = 0; r < 4; ++r)
        csr[r] = 1e-6f + eps[(size_t)(row0 + r) * H_DIM + mycell] * 0.69314718055994531f;

    // prologue: x fragments for t=0 (loads + bf16 convert)
    bf16x8 xf[8];
    #pragma unroll
    for (int kt = 0; kt < 8; ++kt) {
        const float* xp = x + (size_t)arow * (S_DIM * I_DIM) + kt * 32 + kq * 8;
        float4 u0 = reinterpret_cast<const float4*>(xp)[0];
        float4 u1 = reinterpret_cast<const float4*>(xp)[1];
        bf16x8 f;
        f[0]=(bf16_t)u0.x; f[1]=(bf16_t)u0.y; f[2]=(bf16_t)u0.z; f[3]=(bf16_t)u0.w;
        f[4]=(bf16_t)u1.x; f[5]=(bf16_t)u1.y; f[6]=(bf16_t)u1.z; f[7]=(bf16_t)u1.w;
        xf[kt] = f;
    }

    // h(0) = 0 -> first-step h fragments are register zeros (no load needed)
    bf16x8 hf[16];
    #pragma unroll
    for (int kt = 0; kt < 16; ++kt) {
        bf16x8 z;
        #pragma unroll
        for (int j = 0; j < 8; ++j) z[j] = (bf16_t)0.0f;
        hf[kt] = z;
    }

    float  ev[4];       // eps(t+1) prefetch (for Q's sampling)
    f32x2  hv_st[4];    // deferred out_hidden payload

    #pragma unroll 1
    for (int t = 0; t < S_DIM; ++t) {
        bf16_t*       hout = (t & 1) ? hb0 : hb1;
        bf16_t*       cnb  = (t & 1) ? cn1 : cn0;
        unsigned int* hout_u32 = (unsigned int*)hout;
        unsigned int* cnb_u32  = (unsigned int*)cnb;

        // ============ P: gates = h @ W_hh^T + x_t @ W_ih^T =====================
        // h fragments already in registers (loaded during previous Q / zeros).
        f32x4 a0e = {0,0,0,0}, a0o = {0,0,0,0}, a1e = {0,0,0,0}, a1o = {0,0,0,0};
        #pragma unroll
        for (int kt = 0; kt < 16; kt += 2) {
            a0e = __builtin_amdgcn_mfma_f32_16x16x32_bf16(hf[kt],     whh0[kt],     a0e, 0, 0, 0);
            a1e = __builtin_amdgcn_mfma_f32_16x16x32_bf16(hf[kt],     whh1[kt],     a1e, 0, 0, 0);
            a0o = __builtin_amdgcn_mfma_f32_16x16x32_bf16(hf[kt + 1], whh0[kt + 1], a0o, 0, 0, 0);
            a1o = __builtin_amdgcn_mfma_f32_16x16x32_bf16(hf[kt + 1], whh1[kt + 1], a1o, 0, 0, 0);
        }
        // x part: xf prefetched in last barrier window; W_ih streamed from LDS
        #pragma unroll
        for (int kt = 0; kt < 8; kt += 2) {
            bf16x8 w0e = *reinterpret_cast<const bf16x8*>(&s_wih[kt][0][l][0]);
            bf16x8 w1e = *reinterpret_cast<const bf16x8*>(&s_wih[kt][1][l][0]);
            bf16x8 w0o = *reinterpret_cast<const bf16x8*>(&s_wih[kt + 1][0][l][0]);
            bf16x8 w1o = *reinterpret_cast<const bf16x8*>(&s_wih[kt + 1][1][l][0]);
            a0e = __builtin_amdgcn_mfma_f32_16x16x32_bf16(xf[kt],     w0e, a0e, 0, 0, 0);
            a1e = __builtin_amdgcn_mfma_f32_16x16x32_bf16(xf[kt],     w1e, a1e, 0, 0, 0);
            a0o = __builtin_amdgcn_mfma_f32_16x16x32_bf16(xf[kt + 1], w0o, a0o, 0, 0, 0);
            a1o = __builtin_amdgcn_mfma_f32_16x16x32_bf16(xf[kt + 1], w1o, a1o, 0, 0, 0);
        }
        f32x4 a0 = a0e + a0o, a1 = a1e + a1o;

        // ---- pointwise cell update; ONLY h/c (cross-wg) stores issue now ------
        #pragma unroll
        for (int r = 0; r < 4; ++r) {
            float sif = sigm_(a0[r] + bias0);                       // i or f
            float v1  = a1[r] + bias1;
            float go  = (ghalf == 0) ? tanh_(v1) : sigm_(v1);       // g or o
            float fv  = __shfl_xor(sif, 8);
            float ov  = __shfl_xor(go, 8);
            float cn  = fv * csr[r] + sif * go;
            float hn  = ov * tanh_(cn);
            unsigned hcw = ((unsigned)bfbits_(cn) << 16) | (unsigned)bfbits_(hn);
            unsigned pp  = __shfl_xor(hcw, 1);                      // partner cell
            float    hp  = __shfl_xor(hn, 1);
            hv_st[r].x = hn; hv_st[r].y = hp;
            if (ghalf == 0 && !(lr & 1)) {
                const int row  = row0 + r;
                const int cidx = (row * H_DIM + mycell) >> 1;       // u32 index
                unsigned hw = ((pp & 0xFFFFu) << 16) | (hcw & 0xFFFFu);
                unsigned cw = (pp & 0xFFFF0000u)     | (hcw >> 16);
                __hip_atomic_store(hout_u32 + cidx, hw, __ATOMIC_RELAXED, __HIP_MEMORY_SCOPE_AGENT);
                __hip_atomic_store(cnb_u32  + cidx, cw, __ATOMIC_RELAXED, __HIP_MEMORY_SCOPE_AGENT);
            }
        }

        // ============ distributed barrier: arrive(store) -> prefetch -> poll ===
        __threadfence_block();            // drain h/c stores to coherence point
        __syncthreads();
        if (threadIdx.x == 0)             // per-WG flag store, NO RMW
            __hip_atomic_store(&bar[w], (unsigned)(t + 1),
                               __ATOMIC_RELAXED, __HIP_MEMORY_SCOPE_AGENT);

        // hidden under barrier wait: x(t+1) load+convert, eps(t+1) loads
        // (values land in REGISTERS, so the later L2 invalidate is harmless)
        if (t + 1 < S_DIM) {
            #pragma unroll
            for (int kt = 0; kt < 8; ++kt) {
                const float* xp = x + (size_t)arow * (S_DIM * I_DIM)
                                    + (size_t)(t + 1) * I_DIM + kt * 32 + kq * 8;
                float4 u0 = reinterpret_cast<const float4*>(xp)[0];
                float4 u1 = reinterpret_cast<const float4*>(xp)[1];
                bf16x8 f;
                f[0]=(bf16_t)u0.x; f[1]=(bf16_t)u0.y; f[2]=(bf16_t)u0.z; f[3]=(bf16_t)u0.w;
                f[4]=(bf16_t)u1.x; f[5]=(bf16_t)u1.y; f[6]=(bf16_t)u1.z; f[7]=(bf16_t)u1.w;
                xf[kt] = f;
            }
        }
        #pragma unroll
        for (int r = 0; r < 4; ++r)
            ev[r] = eps[(size_t)(t + 1) * BH + (size_t)(row0 + r) * H_DIM + mycell];

        // lane-parallel poll: lane l watches wg l's flag; one load = all 64
        if (wv == 0) {
            const unsigned target = (unsigned)(t + 1);
            while (true) {
                unsigned v = __hip_atomic_load(&bar[l], __ATOMIC_RELAXED,
                                               __HIP_MEMORY_SCOPE_AGENT);
                if (__all((int)(v >= target))) break;
                __builtin_amdgcn_s_sleep(1);
            }
        }
        __syncthreads();
        // agent acquire: invalidate L1/L2 so the cached loads below observe the
        // producers' write-through stores. Nothing persistent lives in cache
        // (weights in regs/LDS; x/eps already in registers) -> near-free.
        __builtin_amdgcn_fence(__ATOMIC_ACQUIRE, "agent");

        // ============ Q: stats = c_new @ G; sample =============================
        // cached c loads, then NEXT-STEP h loads co-issued (hout(t) is visible
        // after the fence; latency hides under Q's MFMAs + sampling). 8 WGs on
        // each XCD share one L2 fill of these lines.
        bf16x8 cf[16];
        #pragma unroll
        for (int kt = 0; kt < 16; ++kt)
            cf[kt] = ld_frag(cnb, arow * H_DIM + kt * 32 + kq * 8);
        #pragma unroll
        for (int kt = 0; kt < 16; ++kt)
            hf[kt] = ld_frag(hout, arow * H_DIM + kt * 32 + kq * 8);

        // deferred output stores (non-temporal; no RFO) issue while cf/hf fill
        if (ghalf == 0 && !(lr & 1)) {
            #pragma unroll
            for (int r = 0; r < 4; ++r)
                __builtin_nontemporal_store(hv_st[r],
                    (f32x2*)(out_hidden + (size_t)(row0 + r) * SH + (size_t)t * H_DIM + mycell));
            if (t == S_DIM - 1) {
                #pragma unroll
                for (int r = 0; r < 4; ++r)
                    __builtin_nontemporal_store(hv_st[r],
                        (f32x2*)(out_hf + (row0 + r) * H_DIM + mycell));
            }
        }

        f32x4 se = {0,0,0,0}, so = {0,0,0,0};
        #pragma unroll
        for (int kt = 0; kt < 16; kt += 2) {
            bf16x8 g0 = *reinterpret_cast<const bf16x8*>(&s_gfr[kt][l][0]);
            bf16x8 g1 = *reinterpret_cast<const bf16x8*>(&s_gfr[kt + 1][l][0]);
            se = __builtin_amdgcn_mfma_f32_16x16x32_bf16(cf[kt],     g0, se, 0, 0, 0);
            so = __builtin_amdgcn_mfma_f32_16x16x32_bf16(cf[kt + 1], g1, so, 0, 0, 0);
        }
        f32x4 st = se + so;
        #pragma unroll
        for (int r = 0; r < 4; ++r) {
            const int row = row0 + r;
            float sv  = st[r];
            float muv = fminf(fmaxf(sv, 1e-6f), 1e6f);
            float sdv = fmaxf(softplus_(sv), 1e-6f);
            float outv = (ghalf == 0) ? muv : sdv;
            float op   = __shfl_xor(outv, 1);       // partner cell's value
            if (!(lr & 1)) {
                float* outp = ((ghalf == 0) ? out_cmu : out_cstd)
                              + (size_t)row * S1H + (size_t)(t + 1) * H_DIM + mycell;
                f32x2 v2; v2.x = outv; v2.y = op;
                __builtin_nontemporal_store(v2, (f32x2*)outp);
            }
            float sd_p = __shfl_xor(outv, 8);       // ghalf==0 gets partner's std
            csr[r] = muv + ev[r] * sd_p;            // register carry of c_s
            if (t == S_DIM - 1 && ghalf == 0)
                __builtin_nontemporal_store(csr[r], out_cf + row * H_DIM + mycell);
        }
        // no second barrier: P(t+1) reads only register hf (loaded above) + csr
    }
}

// ---------------------------------------------------------------------------
extern "C" void kernel_launch(void* const* d_in, const int* in_sizes, int n_in,
                              void* d_out, int out_size, void* d_ws, size_t ws_size,
                              hipStream_t stream) {
    (void)in_sizes; (void)n_in; (void)out_size; (void)ws_size;

    const float* x    = (const float*)d_in[0];  // (B,S,I)
    const float* eps  = (const float*)d_in[1];  // (S+1,B,H)
    const float* W_ih = (const float*)d_in[2];  // (4H,I)
    const float* W_hh = (const float*)d_in[3];  // (4H,H)
    const float* b_ih = (const float*)d_in[4];  // (4H,)
    const float* b_hh = (const float*)d_in[5];  // (4H,)
    const float* Gm   = (const float*)d_in[6];  // (H,2H)

    float* out        = (float*)d_out;
    float* out_hidden = out;                                   // (B,S,H)
    float* out_cmu    = out_hidden + (size_t)B_DIM * SH;       // (B,S+1,H)
    float* out_cstd   = out_cmu + (size_t)B_DIM * S1H;         // (B,S+1,H)
    float* out_hf     = out_cstd + (size_t)B_DIM * S1H;        // (B,H)
    float* out_cf     = out_hf + (size_t)B_DIM * H_DIM;        // (B,H)

    // workspace carve (~260 KB)
    char* wsb = (char*)d_ws;
    bf16_t* hb0 = (bf16_t*)(wsb);                     // 64 KB  h double-buffer
    bf16_t* hb1 = (bf16_t*)(wsb + (1u << 16));        // 64 KB
    bf16_t* cn0 = (bf16_t*)(wsb + 2u * (1u << 16));   // 64 KB  c_new double-buffer
    bf16_t* cn1 = (bf16_t*)(wsb + 3u * (1u << 16));   // 64 KB
    unsigned int* bar = (unsigned int*)(wsb + 4u * (1u << 16)); // barrier (64 slots)

    k_init<<<dim3(128), dim3(256), 0, stream>>>(hb0, bar, out_cmu, out_cstd);
    k_persist<<<dim3(NWG), dim3(256), 0, stream>>>(
        x, eps, W_ih, W_hh, b_ih, b_hh, Gm,
        hb0, hb1, cn0, cn1, bar,
        out_hidden, out_cmu, out_cstd, out_hf, out_cf);
}

// Round 5
// 3705.775 us; speedup vs baseline: 2.2438x; 1.5788x over previous
//
#include <hip/hip_runtime.h>
#include <hip/hip_bf16.h>
#include <math.h>

// Problem dims (fixed by reference)
#define I_DIM 256
#define H_DIM 512
#define B_DIM 64
#define S_DIM 512
#define SH    (S_DIM * H_DIM)        // 262144
#define S1H   ((S_DIM + 1) * H_DIM)  // 262656
#define BH    (B_DIM * H_DIM)        // 32768
#define NGRP  4                      // independent row-groups (16 rows each)
#define GWG   64                     // WGs (cell-slices) per group
#define NWG_TOT (NGRP * GWG)         // 256 WGs x 64 threads (1 wave each)

typedef __bf16 bf16_t;
typedef bf16_t bf16x8 __attribute__((ext_vector_type(8)));
typedef float  f32x4  __attribute__((ext_vector_type(4)));
typedef float  f32x2  __attribute__((ext_vector_type(2)));

__device__ __forceinline__ float sigm_(float x) { return 1.0f / (1.0f + __expf(-x)); }
__device__ __forceinline__ float tanh_(float x) {
    x = fminf(fmaxf(x, -15.f), 15.f);           // avoid exp overflow -> NaN
    float e = __expf(-2.f * x);
    return (1.f - e) / (1.f + e);
}
__device__ __forceinline__ float softplus_(float x) {
    return (x > 20.0f) ? x : log1pf(__expf(x));
}
__device__ __forceinline__ unsigned short bfbits_(float f) {
    return __builtin_bit_cast(unsigned short, (bf16_t)f);
}

// Plain cached 16B fragment load (coherence via per-step agent acquire fence).
__device__ __forceinline__ bf16x8 ld_frag(const bf16_t* base, int elem_idx) {
    return *reinterpret_cast<const bf16x8*>(base + elem_idx);
}

// ---------------------------------------------------------------------------
// Init (every call): zero h0 buffer + ALL 256 barrier slots; write t=0 mu/std
// (c0 = 0 -> stats = 0 exactly -> mu0 = 1e-6, std0 = ln 2).
// ---------------------------------------------------------------------------
__global__ void k_init(bf16_t* __restrict__ hbuf0, unsigned int* __restrict__ bar,
                       float* __restrict__ out_cmu, float* __restrict__ out_cstd) {
    const int i = blockIdx.x * 256 + threadIdx.x;   // b*H + j
    hbuf0[i] = (bf16_t)0.0f;
    const int b = i >> 9, j = i & 511;
    out_cmu [b * S1H + j] = 1e-6f;
    out_cstd[b * S1H + j] = 0.69314718055994531f;
    if (i < NWG_TOT) bar[i] = 0u;
}

// ---------------------------------------------------------------------------
// Persistent kernel: 256 WGs x 64 threads (ONE wave per WG, one WG per CU via
// 96KB LDS). WG (g, wc): row-group g owns batch rows [16g, 16g+16); cell-slice
// wc owns cells [8wc, 8wc+8). The 4 groups are fully independent (separate
// 64-wide store/poll barriers, separate rows of all buffers) -> stragglers
// don't couple across groups, and per-CU exchange ingest drops 128KB -> 32KB.
// Per step:  P(t) = carried x-part + h-part MFMAs -> pointwise -> h/c agent
// stores -> drain -> flag -> [window: x(t+1) load+convert+x-MFMAs, deferred
// output NT stores, eps prefetch] -> poll -> acquire fence -> cf/hf cached
// loads -> Q(t) stats + sampling (outputs register-carried to next window).
// ---------------------------------------------------------------------------
__global__ __launch_bounds__(64, 1) void k_persist(
    const float* __restrict__ x, const float* __restrict__ eps,
    const float* __restrict__ W_ih, const float* __restrict__ W_hh,
    const float* __restrict__ b_ih, const float* __restrict__ b_hh,
    const float* __restrict__ Gm,
    bf16_t* __restrict__ hb0, bf16_t* __restrict__ hb1,
    bf16_t* __restrict__ cn0, bf16_t* __restrict__ cn1,
    unsigned int* __restrict__ bar,
    float* __restrict__ out_hidden, float* __restrict__ out_cmu,
    float* __restrict__ out_cstd, float* __restrict__ out_hf,
    float* __restrict__ out_cf)
{
    // LDS: weight fragments + occupancy pad (96KB total -> exactly 1 WG/CU,
    // so the 256 waves spread across all 256 CUs; no intra-CU L1 contention).
    __shared__ __align__(16) unsigned short s_wih[8][2][64][8];   // 16 KB
    __shared__ __align__(16) unsigned short s_gfr[16][64][8];     // 16 KB
    __shared__ char s_pad[64 * 1024];                             // 64 KB pad
    if (x == nullptr) ((volatile char*)s_pad)[threadIdx.x] = 1;   // keep-alive

    const int wc = blockIdx.x & 63;     // cell-slice (0..63)
    const int g  = blockIdx.x >> 6;     // row-group (0..3)
    const int l  = threadIdx.x;         // lane (single wave)
    const int lr = l & 15;              // MFMA n (B col) / m (A row)
    const int kq = l >> 4;              // k-quad
    const int nsub   = lr & 7;          // cell within slice
    const int ghalf  = lr >> 3;         // 0: i-gate/mu lane, 1: f-gate/std lane
    const int mycell = wc * 8 + nsub;
    const int col0 = ghalf * H_DIM + mycell;   // i/f col in 2048-wide gate space
    const int col1 = 1024 + col0;              // g/o col
    const int gcol = ghalf * H_DIM + mycell;   // mu/std col in 1024-wide stats
    const int row0 = g * 16 + kq * 4;          // batch row base for C layout (+r)
    const int arow = g * 16 + lr;              // batch row for A frags
    unsigned int* barg = bar + g * GWG;        // this group's 64 flags

    // ---- one-time: W_hh -> registers (bf16 frags) -------------------------
    bf16x8 whh0[16], whh1[16];
    #pragma unroll
    for (int kt = 0; kt < 16; ++kt) {
        const float* p0 = W_hh + (size_t)col0 * H_DIM + kt * 32 + kq * 8;
        const float* p1 = W_hh + (size_t)col1 * H_DIM + kt * 32 + kq * 8;
        bf16x8 f0, f1;
        #pragma unroll
        for (int j = 0; j < 8; ++j) { f0[j] = (bf16_t)p0[j]; f1[j] = (bf16_t)p1[j]; }
        whh0[kt] = f0; whh1[kt] = f1;
    }
    // ---- one-time: W_ih, G -> LDS (frag depends only on lane) -------------
    #pragma unroll
    for (int kt = 0; kt < 8; ++kt) {
        const float* p0 = W_ih + (size_t)col0 * I_DIM + kt * 32 + kq * 8;
        const float* p1 = W_ih + (size_t)col1 * I_DIM + kt * 32 + kq * 8;
        bf16x8 f0, f1;
        #pragma unroll
        for (int j = 0; j < 8; ++j) { f0[j] = (bf16_t)p0[j]; f1[j] = (bf16_t)p1[j]; }
        *reinterpret_cast<bf16x8*>(&s_wih[kt][0][l][0]) = f0;
        *reinterpret_cast<bf16x8*>(&s_wih[kt][1][l][0]) = f1;
    }
    #pragma unroll
    for (int kt = 0; kt < 16; ++kt) {
        bf16x8 f;
        #pragma unroll
        for (int j = 0; j < 8; ++j)
            f[j] = (bf16_t)Gm[(size_t)(kt * 32 + kq * 8 + j) * 1024 + gcol];
        *reinterpret_cast<bf16x8*>(&s_gfr[kt][l][0]) = f;
    }
    const float bias0 = b_ih[col0] + b_hh[col0];
    const float bias1 = b_ih[col1] + b_hh[col1];
    __syncthreads();

    // c_s(-1) = mu0 + eps[0]*std0 (register carry; meaningful in ghalf==0 lanes)
    float csr[4];
    #pragma unroll
    for (int r = 0; r < 4; ++r)
        csr[r] = 1e-6f + eps[(size_t)(row0 + r) * H_DIM + mycell] * 0.69314718055994531f;

    // prologue: x(0) -> x-part gate accumulators (carried into iter 0)
    f32x4 ax0e = {0,0,0,0}, ax0o = {0,0,0,0}, ax1e = {0,0,0,0}, ax1o = {0,0,0,0};
    #pragma unroll
    for (int kt = 0; kt < 8; kt += 2) {
        const float* xp = x + (size_t)arow * (S_DIM * I_DIM) + kt * 32 + kq * 8;
        float4 u0 = reinterpret_cast<const float4*>(xp)[0];
        float4 u1 = reinterpret_cast<const float4*>(xp)[1];
        float4 u2 = reinterpret_cast<const float4*>(xp + 32)[0];
        float4 u3 = reinterpret_cast<const float4*>(xp + 32)[1];
        bf16x8 af0, af1;
        af0[0]=(bf16_t)u0.x; af0[1]=(bf16_t)u0.y; af0[2]=(bf16_t)u0.z; af0[3]=(bf16_t)u0.w;
        af0[4]=(bf16_t)u1.x; af0[5]=(bf16_t)u1.y; af0[6]=(bf16_t)u1.z; af0[7]=(bf16_t)u1.w;
        af1[0]=(bf16_t)u2.x; af1[1]=(bf16_t)u2.y; af1[2]=(bf16_t)u2.z; af1[3]=(bf16_t)u2.w;
        af1[4]=(bf16_t)u3.x; af1[5]=(bf16_t)u3.y; af1[6]=(bf16_t)u3.z; af1[7]=(bf16_t)u3.w;
        bf16x8 w0e = *reinterpret_cast<const bf16x8*>(&s_wih[kt][0][l][0]);
        bf16x8 w1e = *reinterpret_cast<const bf16x8*>(&s_wih[kt][1][l][0]);
        bf16x8 w0o = *reinterpret_cast<const bf16x8*>(&s_wih[kt + 1][0][l][0]);
        bf16x8 w1o = *reinterpret_cast<const bf16x8*>(&s_wih[kt + 1][1][l][0]);
        ax0e = __builtin_amdgcn_mfma_f32_16x16x32_bf16(af0, w0e, ax0e, 0, 0, 0);
        ax1e = __builtin_amdgcn_mfma_f32_16x16x32_bf16(af0, w1e, ax1e, 0, 0, 0);
        ax0o = __builtin_amdgcn_mfma_f32_16x16x32_bf16(af1, w0o, ax0o, 0, 0, 0);
        ax1o = __builtin_amdgcn_mfma_f32_16x16x32_bf16(af1, w1o, ax1o, 0, 0, 0);
    }

    // h(0) = 0 -> first-step h fragments are register zeros
    bf16x8 hf[16];
    #pragma unroll
    for (int kt = 0; kt < 16; ++kt) {
        bf16x8 z;
        #pragma unroll
        for (int j = 0; j < 8; ++j) z[j] = (bf16_t)0.0f;
        hf[kt] = z;
    }

    float  ev[4];       // eps(t+1) prefetch (for Q's sampling)
    f32x2  hv_st[4];    // out_hidden(t) payload (stored in next window)
    f32x2  st_out[4];   // cmu/cstd(t+1) payload from Q(t) (stored next window)

    #pragma unroll 1
    for (int t = 0; t < S_DIM; ++t) {
        bf16_t*       hout = (t & 1) ? hb0 : hb1;
        bf16_t*       cnb  = (t & 1) ? cn1 : cn0;
        unsigned int* hout_u32 = (unsigned int*)hout;
        unsigned int* cnb_u32  = (unsigned int*)cnb;

        // ============ P(t): gates = [x-part carried in ax*] + h @ W_hh^T ======
        #pragma unroll
        for (int kt = 0; kt < 16; kt += 2) {
            ax0e = __builtin_amdgcn_mfma_f32_16x16x32_bf16(hf[kt],     whh0[kt],     ax0e, 0, 0, 0);
            ax1e = __builtin_amdgcn_mfma_f32_16x16x32_bf16(hf[kt],     whh1[kt],     ax1e, 0, 0, 0);
            ax0o = __builtin_amdgcn_mfma_f32_16x16x32_bf16(hf[kt + 1], whh0[kt + 1], ax0o, 0, 0, 0);
            ax1o = __builtin_amdgcn_mfma_f32_16x16x32_bf16(hf[kt + 1], whh1[kt + 1], ax1o, 0, 0, 0);
        }
        f32x4 a0 = ax0e + ax0o, a1 = ax1e + ax1o;

        // ---- pointwise cell update; ONLY h/c (cross-wg) stores issue now ------
        #pragma unroll
        for (int r = 0; r < 4; ++r) {
            float sif = sigm_(a0[r] + bias0);                       // i or f
            float v1  = a1[r] + bias1;
            float go  = (ghalf == 0) ? tanh_(v1) : sigm_(v1);       // g or o
            float fv  = __shfl_xor(sif, 8);
            float ov  = __shfl_xor(go, 8);
            float cn  = fv * csr[r] + sif * go;
            float hn  = ov * tanh_(cn);
            unsigned hcw = ((unsigned)bfbits_(cn) << 16) | (unsigned)bfbits_(hn);
            unsigned pp  = __shfl_xor(hcw, 1);                      // partner cell
            float    hp  = __shfl_xor(hn, 1);
            hv_st[r].x = hn; hv_st[r].y = hp;
            if (ghalf == 0 && !(lr & 1)) {
                const int row  = row0 + r;
                const int cidx = (row * H_DIM + mycell) >> 1;       // u32 index
                unsigned hw = ((pp & 0xFFFFu) << 16) | (hcw & 0xFFFFu);
                unsigned cw = (pp & 0xFFFF0000u)     | (hcw >> 16);
                __hip_atomic_store(hout_u32 + cidx, hw, __ATOMIC_RELAXED, __HIP_MEMORY_SCOPE_AGENT);
                __hip_atomic_store(cnb_u32  + cidx, cw, __ATOMIC_RELAXED, __HIP_MEMORY_SCOPE_AGENT);
            }
        }

        // ============ arrive: drain ONLY h/c stores, then flag =================
        __threadfence_block();
        if (l == 0)
            __hip_atomic_store(&barg[wc], (unsigned)(t + 1),
                               __ATOMIC_RELAXED, __HIP_MEMORY_SCOPE_AGENT);

        // ============ window (overlaps other WGs' arrivals) ====================
        // x(t+1) load + convert + x-part MFMAs into fresh accumulators
        ax0e = ax0o = ax1e = ax1o = (f32x4){0,0,0,0};
        if (t + 1 < S_DIM) {
            #pragma unroll
            for (int kt = 0; kt < 8; kt += 2) {
                const float* xp = x + (size_t)arow * (S_DIM * I_DIM)
                                    + (size_t)(t + 1) * I_DIM + kt * 32 + kq * 8;
                float4 u0 = reinterpret_cast<const float4*>(xp)[0];
                float4 u1 = reinterpret_cast<const float4*>(xp)[1];
                float4 u2 = reinterpret_cast<const float4*>(xp + 32)[0];
                float4 u3 = reinterpret_cast<const float4*>(xp + 32)[1];
                bf16x8 af0, af1;
                af0[0]=(bf16_t)u0.x; af0[1]=(bf16_t)u0.y; af0[2]=(bf16_t)u0.z; af0[3]=(bf16_t)u0.w;
                af0[4]=(bf16_t)u1.x; af0[5]=(bf16_t)u1.y; af0[6]=(bf16_t)u1.z; af0[7]=(bf16_t)u1.w;
                af1[0]=(bf16_t)u2.x; af1[1]=(bf16_t)u2.y; af1[2]=(bf16_t)u2.z; af1[3]=(bf16_t)u2.w;
                af1[4]=(bf16_t)u3.x; af1[5]=(bf16_t)u3.y; af1[6]=(bf16_t)u3.z; af1[7]=(bf16_t)u3.w;
                bf16x8 w0e = *reinterpret_cast<const bf16x8*>(&s_wih[kt][0][l][0]);
                bf16x8 w1e = *reinterpret_cast<const bf16x8*>(&s_wih[kt][1][l][0]);
                bf16x8 w0o = *reinterpret_cast<const bf16x8*>(&s_wih[kt + 1][0][l][0]);
                bf16x8 w1o = *reinterpret_cast<const bf16x8*>(&s_wih[kt + 1][1][l][0]);
                ax0e = __builtin_amdgcn_mfma_f32_16x16x32_bf16(af0, w0e, ax0e, 0, 0, 0);
                ax1e = __builtin_amdgcn_mfma_f32_16x16x32_bf16(af0, w1e, ax1e, 0, 0, 0);
                ax0o = __builtin_amdgcn_mfma_f32_16x16x32_bf16(af1, w0o, ax0o, 0, 0, 0);
                ax1o = __builtin_amdgcn_mfma_f32_16x16x32_bf16(af1, w1o, ax1o, 0, 0, 0);
            }
        }
        // deferred outputs: cmu/cstd(t) from Q(t-1); hidden(t) from P(t)
        if (t) {
            if (!(lr & 1)) {
                #pragma unroll
                for (int r = 0; r < 4; ++r) {
                    float* outp = ((ghalf == 0) ? out_cmu : out_cstd)
                                  + (size_t)(row0 + r) * S1H + (size_t)t * H_DIM + mycell;
                    __builtin_nontemporal_store(st_out[r], (f32x2*)outp);
                }
            }
        }
        if (ghalf == 0 && !(lr & 1)) {
            #pragma unroll
            for (int r = 0; r < 4; ++r)
                __builtin_nontemporal_store(hv_st[r],
                    (f32x2*)(out_hidden + (size_t)(row0 + r) * SH + (size_t)t * H_DIM + mycell));
        }
        // eps(t+1) prefetch
        #pragma unroll
        for (int r = 0; r < 4; ++r)
            ev[r] = eps[(size_t)(t + 1) * BH + (size_t)(row0 + r) * H_DIM + mycell];

        // ============ poll: lane l watches group flag l ========================
        {
            const unsigned target = (unsigned)(t + 1);
            while (true) {
                unsigned v = __hip_atomic_load(&barg[l], __ATOMIC_RELAXED,
                                               __HIP_MEMORY_SCOPE_AGENT);
                if (__all((int)(v >= target))) break;
                __builtin_amdgcn_s_sleep(1);
            }
        }
        // agent acquire: invalidate L1/L2 so cached loads see fresh state
        __builtin_amdgcn_fence(__ATOMIC_ACQUIRE, "agent");

        // ============ Q(t): cached c loads + next-step h loads =================
        bf16x8 cf[16];
        #pragma unroll
        for (int kt = 0; kt < 16; ++kt)
            cf[kt] = ld_frag(cnb, arow * H_DIM + kt * 32 + kq * 8);
        #pragma unroll
        for (int kt = 0; kt < 16; ++kt)
            hf[kt] = ld_frag(hout, arow * H_DIM + kt * 32 + kq * 8);

        f32x4 se = {0,0,0,0}, so = {0,0,0,0};
        #pragma unroll
        for (int kt = 0; kt < 16; kt += 2) {
            bf16x8 g0 = *reinterpret_cast<const bf16x8*>(&s_gfr[kt][l][0]);
            bf16x8 g1 = *reinterpret_cast<const bf16x8*>(&s_gfr[kt + 1][l][0]);
            se = __builtin_amdgcn_mfma_f32_16x16x32_bf16(cf[kt],     g0, se, 0, 0, 0);
            so = __builtin_amdgcn_mfma_f32_16x16x32_bf16(cf[kt + 1], g1, so, 0, 0, 0);
        }
        f32x4 st = se + so;
        #pragma unroll
        for (int r = 0; r < 4; ++r) {
            float sv  = st[r];
            float muv = fminf(fmaxf(sv, 1e-6f), 1e6f);
            float sdv = fmaxf(softplus_(sv), 1e-6f);
            float outv = (ghalf == 0) ? muv : sdv;
            float op   = __shfl_xor(outv, 1);       // partner cell's value
            st_out[r].x = outv; st_out[r].y = op;   // stored in next window
            float sd_p = __shfl_xor(outv, 8);       // ghalf==0 gets partner's std
            csr[r] = muv + ev[r] * sd_p;            // register carry of c_s
        }
        // no second barrier: P(t+1) reads only register hf (loaded above) + csr
    }

    // ============ epilogue: final deferred outputs =============================
    if (!(lr & 1)) {
        #pragma unroll
        for (int r = 0; r < 4; ++r) {
            float* outp = ((ghalf == 0) ? out_cmu : out_cstd)
                          + (size_t)(row0 + r) * S1H + (size_t)S_DIM * H_DIM + mycell;
            __builtin_nontemporal_store(st_out[r], (f32x2*)outp);
        }
    }
    if (ghalf == 0 && !(lr & 1)) {
        #pragma unroll
        for (int r = 0; r < 4; ++r)
            __builtin_nontemporal_store(hv_st[r],
                (f32x2*)(out_hf + (row0 + r) * H_DIM + mycell));
    }
    if (ghalf == 0) {
        #pragma unroll
        for (int r = 0; r < 4; ++r)
            __builtin_nontemporal_store(csr[r], out_cf + (row0 + r) * H_DIM + mycell);
    }
}

// ---------------------------------------------------------------------------
extern "C" void kernel_launch(void* const* d_in, const int* in_sizes, int n_in,
                              void* d_out, int out_size, void* d_ws, size_t ws_size,
                              hipStream_t stream) {
    (void)in_sizes; (void)n_in; (void)out_size; (void)ws_size;

    const float* x    = (const float*)d_in[0];  // (B,S,I)
    const float* eps  = (const float*)d_in[1];  // (S+1,B,H)
    const float* W_ih = (const float*)d_in[2];  // (4H,I)
    const float* W_hh = (const float*)d_in[3];  // (4H,H)
    const float* b_ih = (const float*)d_in[4];  // (4H,)
    const float* b_hh = (const float*)d_in[5];  // (4H,)
    const float* Gm   = (const float*)d_in[6];  // (H,2H)

    float* out        = (float*)d_out;
    float* out_hidden = out;                                   // (B,S,H)
    float* out_cmu    = out_hidden + (size_t)B_DIM * SH;       // (B,S+1,H)
    float* out_cstd   = out_cmu + (size_t)B_DIM * S1H;         // (B,S+1,H)
    float* out_hf     = out_cstd + (size_t)B_DIM * S1H;        // (B,H)
    float* out_cf     = out_hf + (size_t)B_DIM * H_DIM;        // (B,H)

    // workspace carve (~260 KB)
    char* wsb = (char*)d_ws;
    bf16_t* hb0 = (bf16_t*)(wsb);                     // 64 KB  h double-buffer
    bf16_t* hb1 = (bf16_t*)(wsb + (1u << 16));        // 64 KB
    bf16_t* cn0 = (bf16_t*)(wsb + 2u * (1u << 16));   // 64 KB  c_new double-buffer
    bf16_t* cn1 = (bf16_t*)(wsb + 3u * (1u << 16));   // 64 KB
    unsigned int* bar = (unsigned int*)(wsb + 4u * (1u << 16)); // barrier (256 slots)

    k_init<<<dim3(128), dim3(256), 0, stream>>>(hb0, bar, out_cmu, out_cstd);
    k_persist<<<dim3(NWG_TOT), dim3(64), 0, stream>>>(
        x, eps, W_ih, W_hh, b_ih, b_hh, Gm,
        hb0, hb1, cn0, cn1, bar,
        out_hidden, out_cmu, out_cstd, out_hf, out_cf);
}